// Round 1
// baseline (297.759 us; speedup 1.0000x reference)
//
#include <hip/hip_runtime.h>
#include <math.h>

// Problem constants (from reference): B=64, D=128, N=500000, K+1=4096
constexpr int Bb   = 64;
constexpr int Dd   = 128;
constexpr int KP1  = 4096;
constexpr long NMEM = 500000L * 128;   // elements per memory bank
constexpr int BK   = Bb * KP1;         // 262144 elements per score output

// Output layout (flat, in reference return order):
// [0, BK)                 out_image
// [BK, 2*BK)              out_gene
// [2*BK, 2*BK+NMEM)       new_memory_image
// [2*BK+NMEM, 2*BK+2NMEM) new_memory_gene

// Fused kernel:
//  blocks [0,128): scores + softmax. blockIdx.x>>1 = b, &1 = which.
//    which==0: w = memory_gene, x = image  -> out_image
//    which==1: w = memory_image, x = gene  -> out_gene
//  blocks [128, 128+nCopy): grid-stride float4 copy of both banks into d_out.
__global__ __launch_bounds__(512) void fused_scores_copy(
    const float* __restrict__ image, const float* __restrict__ gene,
    const float* __restrict__ mem_image, const float* __restrict__ mem_gene,
    const int* __restrict__ idx, float* __restrict__ out, int nCopyBlocks)
{
    if (blockIdx.x >= 128) {
        // ---- streaming copy of both memory banks ----
        const long nvec = (2 * NMEM) / 4;          // 32M float4
        const long half = NMEM / 4;
        long t = (long)(blockIdx.x - 128) * 512 + threadIdx.x;
        const long stride = (long)nCopyBlocks * 512;
        const float4* si = (const float4*)mem_image;
        const float4* sg = (const float4*)mem_gene;
        float4* dst = (float4*)(out + 2 * BK);
        for (long i = t; i < nvec; i += stride) {
            dst[i] = (i < half) ? si[i] : sg[i - half];
        }
        return;
    }

    // ---- scores + softmax ----
    const int b     = blockIdx.x >> 1;
    const int which = blockIdx.x & 1;
    const float* w = which ? mem_image : mem_gene;
    const float* x = which ? gene : image;
    float* o = out + (long)which * BK + (long)b * KP1;

    __shared__ float sv[KP1];   // 16 KB score row
    __shared__ float red[8];

    const int tid = threadIdx.x;   // 0..511
    const int lg  = tid & 15;      // lane within 16-lane group (covers one 512B row)
    const int grp = tid >> 4;      // 0..31 groups

    // each lane keeps its fixed 8-float slice of x in registers
    float4 x0 = *(const float4*)(x + b * Dd + lg * 8);
    float4 x1 = *(const float4*)(x + b * Dd + lg * 8 + 4);

    const int* idxb = idx + (long)b * KP1;
    for (int k = grp; k < KP1; k += 32) {
        long row = idxb[k];
        const float4* wr = (const float4*)(w + row * Dd + lg * 8);
        float4 w0 = wr[0];
        float4 w1 = wr[1];
        float d = w0.x*x0.x + w0.y*x0.y + w0.z*x0.z + w0.w*x0.w
                + w1.x*x1.x + w1.y*x1.y + w1.z*x1.z + w1.w*x1.w;
        // reduce across the 16-lane group
        d += __shfl_xor(d, 1);
        d += __shfl_xor(d, 2);
        d += __shfl_xor(d, 4);
        d += __shfl_xor(d, 8);
        if (lg == 0) sv[k] = d;
    }
    __syncthreads();

    // block max
    float m = -INFINITY;
    for (int k = tid; k < KP1; k += 512) m = fmaxf(m, sv[k]);
    #pragma unroll
    for (int off = 1; off < 64; off <<= 1) m = fmaxf(m, __shfl_xor(m, off));
    if ((tid & 63) == 0) red[tid >> 6] = m;
    __syncthreads();
    if (tid < 64) {
        float tv = (tid < 8) ? red[tid] : -INFINITY;
        #pragma unroll
        for (int off = 1; off < 8; off <<= 1) tv = fmaxf(tv, __shfl_xor(tv, off));
        if (tid == 0) red[0] = tv;
    }
    __syncthreads();
    m = red[0];
    __syncthreads();   // red is about to be reused

    // exp + block sum
    float sum = 0.f;
    for (int k = tid; k < KP1; k += 512) {
        float e = expf(sv[k] - m);
        sv[k] = e;
        sum += e;
    }
    #pragma unroll
    for (int off = 1; off < 64; off <<= 1) sum += __shfl_xor(sum, off);
    if ((tid & 63) == 0) red[tid >> 6] = sum;
    __syncthreads();
    if (tid < 64) {
        float tv = (tid < 8) ? red[tid] : 0.f;
        #pragma unroll
        for (int off = 1; off < 8; off <<= 1) tv += __shfl_xor(tv, off);
        if (tid == 0) red[0] = tv;
    }
    __syncthreads();
    const float inv = 1.0f / red[0];
    for (int k = tid; k < KP1; k += 512) o[k] = sv[k] * inv;
}

// Momentum scatter-update of the 64 rows per bank, written AFTER the copy.
// grid (64, 2), 128 threads (one per d).
__global__ __launch_bounds__(128) void momentum_update(
    const float* __restrict__ image, const float* __restrict__ gene,
    const float* __restrict__ mem_image, const float* __restrict__ mem_gene,
    const int* __restrict__ index, float* __restrict__ out)
{
    const int b     = blockIdx.x;
    const int which = blockIdx.y;   // 0 -> image bank, 1 -> gene bank
    const float* mem = which ? mem_gene : mem_image;
    const float* x   = which ? gene : image;
    float* o = out + 2 * BK + (long)which * NMEM;

    const long row = index[b];
    const int d = threadIdx.x;   // 0..127

    float p = mem[row * Dd + d] * 0.5f + x[(long)b * Dd + d] * 0.5f;
    float ss = p * p;
    #pragma unroll
    for (int off = 1; off < 64; off <<= 1) ss += __shfl_xor(ss, off);
    __shared__ float r2[2];
    if ((d & 63) == 0) r2[d >> 6] = ss;
    __syncthreads();
    const float inv = 1.0f / sqrtf(r2[0] + r2[1]);
    o[row * Dd + d] = p * inv;
}

extern "C" void kernel_launch(void* const* d_in, const int* in_sizes, int n_in,
                              void* d_out, int out_size, void* d_ws, size_t ws_size,
                              hipStream_t stream) {
    const float* image     = (const float*)d_in[0];
    const float* gene      = (const float*)d_in[1];
    const float* mem_image = (const float*)d_in[2];
    const float* mem_gene  = (const float*)d_in[3];
    const int*   index     = (const int*)d_in[4];
    const int*   idx       = (const int*)d_in[5];
    float* out = (float*)d_out;

    const int nCopy = 1920;
    fused_scores_copy<<<dim3(128 + nCopy), 512, 0, stream>>>(
        image, gene, mem_image, mem_gene, idx, out, nCopy);
    momentum_update<<<dim3(64, 2), 128, 0, stream>>>(
        image, gene, mem_image, mem_gene, index, out);
}

// Round 3
// 214.184 us; speedup vs baseline: 1.3902x; 1.3902x over previous
//
#include <hip/hip_runtime.h>
#include <math.h>

// Problem constants (from reference): B=64, D=128, N=500000, K+1=4096
constexpr int Bb   = 64;
constexpr int Dd   = 128;
constexpr int KP1  = 4096;
constexpr long NMEM = 500000L * 128;   // elements per memory bank
constexpr int BK   = Bb * KP1;         // 262144 elements per score output

// native clang vector type (usable with __builtin_nontemporal_store)
typedef float f4 __attribute__((ext_vector_type(4)));

// Output layout (flat, reference return order):
// [0, BK)                 out_image
// [BK, 2*BK)              out_gene
// [2*BK, 2*BK+NMEM)       new_memory_image
// [2*BK+NMEM, 2*BK+2NMEM) new_memory_gene

__device__ __forceinline__ float dot8(float4 a, float4 b, float4 x0, float4 x1) {
    return a.x*x0.x + a.y*x0.y + a.z*x0.z + a.w*x0.w
         + b.x*x1.x + b.y*x1.y + b.z*x1.z + b.w*x1.w;
}

// Fused kernel:
//  blocks [0,128): scores + softmax for (b = blk>>1, which = blk&1).
//    which==0: w = memory_gene, x = image  -> out_image
//    which==1: w = memory_image, x = gene  -> out_gene
//  blocks [128, 128+nCopy): streaming bank copy, bank = (blk-128)&1.
__global__ __launch_bounds__(512) void fused_scores_copy(
    const float* __restrict__ image, const float* __restrict__ gene,
    const float* __restrict__ mem_image, const float* __restrict__ mem_gene,
    const int* __restrict__ idx, float* __restrict__ out, int nCopyBlocks)
{
    const int tid = threadIdx.x;

    if (blockIdx.x >= 128) {
        // ---- streaming copy, one bank per block (no per-iter select) ----
        const long half = NMEM / 4;               // float4 per bank (16M)
        const int  cb   = blockIdx.x - 128;
        const int  bank = cb & 1;                 // 0 -> image, 1 -> gene
        const f4* src = bank ? (const f4*)mem_gene : (const f4*)mem_image;
        f4* dst = (f4*)(out + 2 * BK) + (long)bank * half;
        const long stride = (long)(nCopyBlocks >> 1) * 512;
        long i = (long)(cb >> 1) * 512 + tid;
        // 4x unrolled: 4 independent loads in flight per thread
        for (; i + 3 * stride < half; i += 4 * stride) {
            f4 v0 = src[i];
            f4 v1 = src[i + stride];
            f4 v2 = src[i + 2 * stride];
            f4 v3 = src[i + 3 * stride];
            __builtin_nontemporal_store(v0, dst + i);
            __builtin_nontemporal_store(v1, dst + i + stride);
            __builtin_nontemporal_store(v2, dst + i + 2 * stride);
            __builtin_nontemporal_store(v3, dst + i + 3 * stride);
        }
        for (; i < half; i += stride)
            __builtin_nontemporal_store(src[i], dst + i);
        return;
    }

    // ---- scores + softmax ----
    const int b     = blockIdx.x >> 1;
    const int which = blockIdx.x & 1;
    const float* w = which ? mem_image : mem_gene;
    const float* x = which ? gene : image;
    float* o = out + (long)which * BK + (long)b * KP1;

    __shared__ int   sidx[KP1];   // 16 KB: prefetched gather indices
    __shared__ float sv[KP1];     // 16 KB: score row
    __shared__ float red[8];

    // vectorized idx preload: 4096 ints = 1024 int4, 512 threads x 2
    {
        const int4* s4 = (const int4*)(idx + (long)b * KP1);
        int4* d4 = (int4*)sidx;
        d4[tid]       = s4[tid];
        d4[tid + 512] = s4[tid + 512];
    }

    const int lg  = tid & 15;      // lane within 16-lane group (one 512B row)
    const int grp = tid >> 4;      // 0..31 groups

    float4 x0 = *(const float4*)(x + b * Dd + lg * 8);
    float4 x1 = *(const float4*)(x + b * Dd + lg * 8 + 4);
    __syncthreads();

    // gather + dot, 4x unrolled: 8 float4 loads in flight per lane
    for (int j = 0; j < 128; j += 4) {
        const int k0 = grp + (j + 0) * 32;
        const int k1 = grp + (j + 1) * 32;
        const int k2 = grp + (j + 2) * 32;
        const int k3 = grp + (j + 3) * 32;
        const float4* r0 = (const float4*)(w + (long)sidx[k0] * Dd + lg * 8);
        const float4* r1 = (const float4*)(w + (long)sidx[k1] * Dd + lg * 8);
        const float4* r2 = (const float4*)(w + (long)sidx[k2] * Dd + lg * 8);
        const float4* r3 = (const float4*)(w + (long)sidx[k3] * Dd + lg * 8);
        float4 a0 = r0[0], b0 = r0[1];
        float4 a1 = r1[0], b1 = r1[1];
        float4 a2 = r2[0], b2 = r2[1];
        float4 a3 = r3[0], b3 = r3[1];
        float d0 = dot8(a0, b0, x0, x1);
        float d1 = dot8(a1, b1, x0, x1);
        float d2 = dot8(a2, b2, x0, x1);
        float d3 = dot8(a3, b3, x0, x1);
        d0 += __shfl_xor(d0, 1); d1 += __shfl_xor(d1, 1);
        d2 += __shfl_xor(d2, 1); d3 += __shfl_xor(d3, 1);
        d0 += __shfl_xor(d0, 2); d1 += __shfl_xor(d1, 2);
        d2 += __shfl_xor(d2, 2); d3 += __shfl_xor(d3, 2);
        d0 += __shfl_xor(d0, 4); d1 += __shfl_xor(d1, 4);
        d2 += __shfl_xor(d2, 4); d3 += __shfl_xor(d3, 4);
        d0 += __shfl_xor(d0, 8); d1 += __shfl_xor(d1, 8);
        d2 += __shfl_xor(d2, 8); d3 += __shfl_xor(d3, 8);
        if (lg == 0) {
            sv[k0] = d0; sv[k1] = d1; sv[k2] = d2; sv[k3] = d3;
        }
    }
    __syncthreads();

    // block max
    float m = -INFINITY;
    for (int k = tid; k < KP1; k += 512) m = fmaxf(m, sv[k]);
    #pragma unroll
    for (int off = 1; off < 64; off <<= 1) m = fmaxf(m, __shfl_xor(m, off));
    if ((tid & 63) == 0) red[tid >> 6] = m;
    __syncthreads();
    if (tid < 64) {
        float tv = (tid < 8) ? red[tid] : -INFINITY;
        #pragma unroll
        for (int off = 1; off < 8; off <<= 1) tv = fmaxf(tv, __shfl_xor(tv, off));
        if (tid == 0) red[0] = tv;
    }
    __syncthreads();
    m = red[0];
    __syncthreads();   // red about to be reused

    // exp + block sum
    float sum = 0.f;
    for (int k = tid; k < KP1; k += 512) {
        float e = expf(sv[k] - m);
        sv[k] = e;
        sum += e;
    }
    #pragma unroll
    for (int off = 1; off < 64; off <<= 1) sum += __shfl_xor(sum, off);
    if ((tid & 63) == 0) red[tid >> 6] = sum;
    __syncthreads();
    if (tid < 64) {
        float tv = (tid < 8) ? red[tid] : 0.f;
        #pragma unroll
        for (int off = 1; off < 8; off <<= 1) tv += __shfl_xor(tv, off);
        if (tid == 0) red[0] = tv;
    }
    __syncthreads();
    const float inv = 1.0f / red[0];
    for (int k = tid; k < KP1; k += 512) o[k] = sv[k] * inv;
}

// Momentum scatter-update of the 64 rows per bank, AFTER the copy (stream order).
// grid (64, 2), 128 threads (one per d).
__global__ __launch_bounds__(128) void momentum_update(
    const float* __restrict__ image, const float* __restrict__ gene,
    const float* __restrict__ mem_image, const float* __restrict__ mem_gene,
    const int* __restrict__ index, float* __restrict__ out)
{
    const int b     = blockIdx.x;
    const int which = blockIdx.y;   // 0 -> image bank, 1 -> gene bank
    const float* mem = which ? mem_gene : mem_image;
    const float* x   = which ? gene : image;
    float* o = out + 2 * BK + (long)which * NMEM;

    const long row = index[b];
    const int d = threadIdx.x;   // 0..127

    float p = mem[row * Dd + d] * 0.5f + x[(long)b * Dd + d] * 0.5f;
    float ss = p * p;
    #pragma unroll
    for (int off = 1; off < 64; off <<= 1) ss += __shfl_xor(ss, off);
    __shared__ float r2[2];
    if ((d & 63) == 0) r2[d >> 6] = ss;
    __syncthreads();
    const float inv = 1.0f / sqrtf(r2[0] + r2[1]);
    o[row * Dd + d] = p * inv;
}

extern "C" void kernel_launch(void* const* d_in, const int* in_sizes, int n_in,
                              void* d_out, int out_size, void* d_ws, size_t ws_size,
                              hipStream_t stream) {
    const float* image     = (const float*)d_in[0];
    const float* gene      = (const float*)d_in[1];
    const float* mem_image = (const float*)d_in[2];
    const float* mem_gene  = (const float*)d_in[3];
    const int*   index     = (const int*)d_in[4];
    const int*   idx       = (const int*)d_in[5];
    float* out = (float*)d_out;

    const int nCopy = 1920;   // even: half image bank, half gene bank
    fused_scores_copy<<<dim3(128 + nCopy), 512, 0, stream>>>(
        image, gene, mem_image, mem_gene, idx, out, nCopy);
    momentum_update<<<dim3(64, 2), 128, 0, stream>>>(
        image, gene, mem_image, mem_gene, index, out);
}